// Round 6
// baseline (112.655 us; speedup 1.0000x reference)
//
#include <hip/hip_runtime.h>

#define NB 4
#define SS 2048
#define DMODEL 1024
#define DHEAD 64
// SCALE = sqrt(1024) = 32 exactly; folded into Wt for mode 0 (and bias at use).
// Softmax WITHOUT max subtraction: s ~ N(0,0.25), exp safe in f32.
// Softmax over the QUERY axis (reference quirk): r[k] = 1/sum_q exp(s[q,k]).
// out = (exp(S).*r) @ V  +  mask @ V   (two GEMMs; no P materialization)

typedef __bf16 bf16x8 __attribute__((ext_vector_type(8)));
typedef __bf16 bf16x4 __attribute__((ext_vector_type(4)));
typedef float f32x4 __attribute__((ext_vector_type(4)));

#define MFMA16(a, b, c) __builtin_amdgcn_mfma_f32_16x16x32_bf16((a), (b), (c), 0, 0, 0)

// ---------------- Kernel 0: transpose W -> Wt[mode][n][k] bf16 ----------------
__global__ __launch_bounds__(256) void k0_wt(
    const float* __restrict__ Wq, const float* __restrict__ Wk,
    const float* __restrict__ Wv, __bf16* __restrict__ Wt)
{
    int t = blockIdx.x * 256 + threadIdx.x;
    int m = t >> 13;
    int rem = t & 8191;
    int n  = rem >> 7;
    int k0 = (rem & 127) << 3;
    const float* W = (m == 0) ? Wq : (m == 1 ? Wk : Wv);
    const float s = (m == 0) ? 0.03125f : 1.0f;
    __bf16* o = Wt + ((size_t)m * 64 + n) * DMODEL + k0;
    #pragma unroll
    for (int i = 0; i < 8; ++i)
        o[i] = (__bf16)(W[(size_t)(k0 + i) * DHEAD + n] * s);
}

// ---------------- Kernel 1: fused Q/K/V projection ----------------
__global__ __launch_bounds__(256) void k1_fused(
    const float* __restrict__ x, const __bf16* __restrict__ Wt,
    const float* __restrict__ bq, const float* __restrict__ bk,
    const float* __restrict__ bv,
    __bf16* __restrict__ Qo, __bf16* __restrict__ Ko, __bf16* __restrict__ Vt)
{
    __shared__ f32x4 red[3][12][64];
    const int tid = threadIdx.x;
    const int wid = tid >> 6;
    const int lane = tid & 63;
    const int l15 = lane & 15;
    const int g = lane >> 4;
    const int row0 = blockIdx.x * 16;

    f32x4 acc[12];
    #pragma unroll
    for (int f = 0; f < 12; ++f) acc[f] = (f32x4){0.f, 0.f, 0.f, 0.f};

    const float* xrow = x + (size_t)(row0 + l15) * DMODEL + wid * 256 + g * 8;
    const __bf16* wbase = Wt + (size_t)l15 * DMODEL + wid * 256 + g * 8;

    for (int c = 0; c < 8; ++c) {
        f32x4 a0 = *(const f32x4*)(xrow + c * 32);
        f32x4 a1 = *(const f32x4*)(xrow + c * 32 + 4);
        bf16x8 af;
        af[0]=(__bf16)a0[0]; af[1]=(__bf16)a0[1]; af[2]=(__bf16)a0[2]; af[3]=(__bf16)a0[3];
        af[4]=(__bf16)a1[0]; af[5]=(__bf16)a1[1]; af[6]=(__bf16)a1[2]; af[7]=(__bf16)a1[3];
        #pragma unroll
        for (int f = 0; f < 12; ++f) {
            const int md = f >> 2, nt = f & 3;
            bf16x8 bfr = *(const bf16x8*)(wbase + ((size_t)(md * 64 + nt * 16) * DMODEL) + c * 32);
            acc[f] = MFMA16(af, bfr, acc[f]);
        }
    }

    if (wid != 0) {
        #pragma unroll
        for (int f = 0; f < 12; ++f) red[wid - 1][f][lane] = acc[f];
    }
    __syncthreads();
    if (wid == 0) {
        const int b  = row0 >> 11;
        const int s0 = row0 & 2047;
        #pragma unroll
        for (int f = 0; f < 12; ++f) {
            f32x4 a = acc[f] + red[0][f][lane] + red[1][f][lane] + red[2][f][lane];
            const int md = f >> 2, nt = f & 3;
            const int n = nt * 16 + l15;
            const float* bias = (md == 0) ? bq : (md == 1 ? bk : bv);
            const float bscale = (md == 0) ? 0.03125f : 1.0f;
            float bvl = bias[n] * bscale;
            #pragma unroll
            for (int r = 0; r < 4; ++r) {
                float o = a[r] + bvl;
                int sr = s0 + g * 4 + r;
                if (md == 0)      Qo[((size_t)b * SS + sr) * DHEAD + n] = (__bf16)o;
                else if (md == 1) Ko[((size_t)b * SS + sr) * DHEAD + n] = (__bf16)o;
                else              Vt[((size_t)b * DHEAD + n) * SS + sr] = (__bf16)o;
            }
        }
    }
}

// ---------------- Kernel 2: column exp-sum partials (no P store) ------------
// Swapped mfma(K,Q): lane holds S[q=l15][k=k0+4g+r] -> colsum accumulates in
// registers across the q-loop. grid 1024 = 4b x 16 kg(128k) x 16 qs(128q).
__global__ __launch_bounds__(256) void k2_cs(
    const __bf16* __restrict__ Qb, const __bf16* __restrict__ Kb,
    float* __restrict__ partial)
{
    __shared__ float ls[4][16];
    const int tid = threadIdx.x;
    const int wid = tid >> 6;
    const int lane = tid & 63;
    const int l15 = lane & 15;
    const int g = lane >> 4;
    const int bx = blockIdx.x;
    const int b  = bx >> 8;
    const int rem = bx & 255;
    const int kg = rem >> 4;
    const int qs = rem & 15;
    const int k0 = kg * 128 + wid * 32;

    const __bf16* kp0 = Kb + ((size_t)(b * SS + k0 + l15)) * DHEAD + g * 8;
    bf16x8 ka00 = *(const bf16x8*)(kp0);
    bf16x8 ka01 = *(const bf16x8*)(kp0 + 32);
    const __bf16* kp1 = kp0 + 16 * DHEAD;
    bf16x8 ka10 = *(const bf16x8*)(kp1);
    bf16x8 ka11 = *(const bf16x8*)(kp1 + 32);

    f32x4 cs0 = (f32x4){0.f, 0.f, 0.f, 0.f};
    f32x4 cs1 = (f32x4){0.f, 0.f, 0.f, 0.f};

    #pragma unroll 2
    for (int j = 0; j < 8; ++j) {
        const int qrow = qs * 128 + j * 16 + l15;
        const __bf16* qp = Qb + ((size_t)(b * SS + qrow)) * DHEAD + g * 8;
        bf16x8 qb0 = *(const bf16x8*)(qp);
        bf16x8 qb1 = *(const bf16x8*)(qp + 32);
        f32x4 s0 = (f32x4){0.f, 0.f, 0.f, 0.f};
        s0 = MFMA16(ka00, qb0, s0);
        s0 = MFMA16(ka01, qb1, s0);
        f32x4 s1 = (f32x4){0.f, 0.f, 0.f, 0.f};
        s1 = MFMA16(ka10, qb0, s1);
        s1 = MFMA16(ka11, qb1, s1);
        #pragma unroll
        for (int r = 0; r < 4; ++r) {
            cs0[r] += __expf(s0[r]);
            cs1[r] += __expf(s1[r]);
        }
    }
    // sum over the 16 q-columns held across l15 lanes
    #pragma unroll
    for (int off = 1; off < 16; off <<= 1) {
        #pragma unroll
        for (int r = 0; r < 4; ++r) {
            cs0[r] += __shfl_xor(cs0[r], off);
            cs1[r] += __shfl_xor(cs1[r], off);
        }
    }
    if (l15 == 0) {
        float* pp = partial + (size_t)qs * (NB * SS) + b * SS + k0 + 4 * g;
        *(f32x4*)(pp)      = cs0;   // k = k0    + 4g + r
        *(f32x4*)(pp + 16) = cs1;   // k = k0+16 + 4g + r
    }
}

// k2b: r[k] = 1 / sum_qs partial[qs][k]
__global__ __launch_bounds__(256) void k2b(
    const float* __restrict__ partial, float* __restrict__ rarr)
{
    int i = blockIdx.x * 256 + threadIdx.x;   // 0..8191
    float s = 0.f;
    #pragma unroll
    for (int qs = 0; qs < 16; ++qs) s += partial[(size_t)qs * (NB * SS) + i];
    rarr[i] = 1.0f / s;
}

// ---------------- Kernel B: out = (exp(S).*r) @ V  (recompute, tiny data) ---
// grid 512 = 4b x 128 q-tiles; block 256 = 4 waves, each a 512-k quarter.
// Per 32-k chunk: swapped QK mfma -> lane holds e[k=4g+r] for q=l15 -> exp*r
// in registers -> in-register shuffle transpose to PV A-frag (af[i] holds
// k=8g+i for q=l15): src lane = l15 + 16*((2g+(i>>2))&3), value e0/e1[i&3],
// select by dest g<2. Then 4 PV MFMAs. No LDS in the loop; direct stores.
__global__ __launch_bounds__(256) void kb_pv(
    const __bf16* __restrict__ Qb, const __bf16* __restrict__ Kb,
    const __bf16* __restrict__ Vt, const float* __restrict__ rarr,
    float* __restrict__ out)
{
    __shared__ f32x4 red[4][4][64];           // 16 KB
    const int tid = threadIdx.x;
    const int wid = tid >> 6;
    const int lane = tid & 63;
    const int l15 = lane & 15;
    const int g = lane >> 4;
    const int bx = blockIdx.x;
    const int b  = bx >> 7;
    const int q0 = (bx & 127) * 16;

    // hoisted Q B-frag (fixed q-tile)
    const __bf16* qp = Qb + ((size_t)(b * SS + q0 + l15)) * DHEAD + g * 8;
    bf16x8 qb0 = *(const bf16x8*)(qp);
    bf16x8 qb1 = *(const bf16x8*)(qp + 32);

    f32x4 acc[4];
    #pragma unroll
    for (int nt = 0; nt < 4; ++nt) acc[nt] = (f32x4){0.f, 0.f, 0.f, 0.f};
    const __bf16* vbase = Vt + (size_t)b * DHEAD * SS;
    const float* rrow = rarr + b * SS;

    #pragma unroll 2
    for (int c = 0; c < 16; ++c) {
        const int k0 = wid * 512 + c * 32;
        const __bf16* kp0 = Kb + ((size_t)(b * SS + k0 + l15)) * DHEAD + g * 8;
        bf16x8 ka00 = *(const bf16x8*)(kp0);
        bf16x8 ka01 = *(const bf16x8*)(kp0 + 32);
        const __bf16* kp1 = kp0 + 16 * DHEAD;
        bf16x8 ka10 = *(const bf16x8*)(kp1);
        bf16x8 ka11 = *(const bf16x8*)(kp1 + 32);

        f32x4 s0 = (f32x4){0.f, 0.f, 0.f, 0.f};
        s0 = MFMA16(ka00, qb0, s0);
        s0 = MFMA16(ka01, qb1, s0);
        f32x4 s1 = (f32x4){0.f, 0.f, 0.f, 0.f};
        s1 = MFMA16(ka10, qb0, s1);
        s1 = MFMA16(ka11, qb1, s1);

        f32x4 rv0 = *(const f32x4*)(rrow + k0 + 4 * g);
        f32x4 rv1 = *(const f32x4*)(rrow + k0 + 16 + 4 * g);
        f32x4 e0, e1;
        #pragma unroll
        for (int r = 0; r < 4; ++r) {
            e0[r] = __expf(s0[r]) * rv0[r];
            e1[r] = __expf(s1[r]) * rv1[r];
        }
        // shuffle transpose: af[i] = P~[q=l15][k0 + 8g + i]
        bf16x8 af;
        #pragma unroll
        for (int i = 0; i < 8; ++i) {
            int src = l15 + 16 * ((2 * g + (i >> 2)) & 3);
            float v0 = __shfl(e0[i & 3], src);
            float v1 = __shfl(e1[i & 3], src);
            af[i] = (__bf16)(g < 2 ? v0 : v1);
        }
        #pragma unroll
        for (int nt = 0; nt < 4; ++nt) {
            bf16x8 vb = *(const bf16x8*)(vbase + (size_t)(nt * 16 + l15) * SS + k0 + g * 8);
            acc[nt] = MFMA16(af, vb, acc[nt]);
        }
    }
    #pragma unroll
    for (int nt = 0; nt < 4; ++nt) red[wid][nt][lane] = acc[nt];
    __syncthreads();
    if (wid == 0) {
        #pragma unroll
        for (int nt = 0; nt < 4; ++nt) {
            f32x4 a = red[0][nt][lane] + red[1][nt][lane]
                    + red[2][nt][lane] + red[3][nt][lane];
            #pragma unroll
            for (int r = 0; r < 4; ++r)
                out[((size_t)(b * SS + q0 + g * 4 + r)) * DHEAD + nt * 16 + l15] = a[r];
        }
    }
}

// ---------------- Kernel A: out += mask @ V  (pure streaming GEMM) ----------
// grid 512 = 4b x 128 q-tiles; block 256 = 4 waves, each a 512-k quarter.
// Per 32-k chunk: 2 mask f32x4 loads -> bf16 A-frag, 4 V B-frags, 4 MFMA.
// No exp, no shuffles, no serial chain. Epilogue: out += (runs after kb_pv).
__global__ __launch_bounds__(256) void ka_mv(
    const __bf16* __restrict__ Vt, const float* __restrict__ mask,
    float* __restrict__ out)
{
    __shared__ f32x4 red[4][4][64];           // 16 KB
    const int tid = threadIdx.x;
    const int wid = tid >> 6;
    const int lane = tid & 63;
    const int l15 = lane & 15;
    const int g = lane >> 4;
    const int bx = blockIdx.x;
    const int b  = bx >> 7;
    const int q0 = (bx & 127) * 16;

    f32x4 acc[4];
    #pragma unroll
    for (int nt = 0; nt < 4; ++nt) acc[nt] = (f32x4){0.f, 0.f, 0.f, 0.f};
    const float* mrow = mask + ((size_t)(b * SS + q0 + l15)) * SS + wid * 512 + g * 8;
    const __bf16* vbase = Vt + (size_t)b * DHEAD * SS + wid * 512 + g * 8;

    #pragma unroll 2
    for (int c = 0; c < 16; ++c) {
        f32x4 m0 = *(const f32x4*)(mrow + c * 32);
        f32x4 m1 = *(const f32x4*)(mrow + c * 32 + 4);
        bf16x8 af;
        #pragma unroll
        for (int i = 0; i < 4; ++i) { af[i] = (__bf16)m0[i]; af[i + 4] = (__bf16)m1[i]; }
        #pragma unroll
        for (int nt = 0; nt < 4; ++nt) {
            bf16x8 vb = *(const bf16x8*)(vbase + (size_t)(nt * 16 + l15) * SS + c * 32);
            acc[nt] = MFMA16(af, vb, acc[nt]);
        }
    }
    #pragma unroll
    for (int nt = 0; nt < 4; ++nt) red[wid][nt][lane] = acc[nt];
    __syncthreads();
    if (wid == 0) {
        #pragma unroll
        for (int nt = 0; nt < 4; ++nt) {
            f32x4 a = red[0][nt][lane] + red[1][nt][lane]
                    + red[2][nt][lane] + red[3][nt][lane];
            #pragma unroll
            for (int r = 0; r < 4; ++r) {
                size_t o = ((size_t)(b * SS + q0 + g * 4 + r)) * DHEAD + nt * 16 + l15;
                out[o] += a[r];
            }
        }
    }
}

extern "C" void kernel_launch(void* const* d_in, const int* in_sizes, int n_in,
                              void* d_out, int out_size, void* d_ws, size_t ws_size,
                              hipStream_t stream)
{
    const float* x    = (const float*)d_in[0];
    const float* mask = (const float*)d_in[1];
    const float* Wq   = (const float*)d_in[2];
    const float* bq   = (const float*)d_in[3];
    const float* Wk   = (const float*)d_in[4];
    const float* bk   = (const float*)d_in[5];
    const float* Wv   = (const float*)d_in[6];
    const float* bv   = (const float*)d_in[7];
    float* out = (float*)d_out;

    // ws layout (~4 MB): Qbf 1MB | Kbf 1MB | Vt 1MB | rarr 32KB | partial 512KB | Wt 384KB
    char* ws = (char*)d_ws;
    __bf16* Qbf   = (__bf16*)(ws);
    __bf16* Kbf   = (__bf16*)(ws + (1u << 20));
    __bf16* Vt    = (__bf16*)(ws + (2u << 20));
    float*  rarr  = (float*)(ws + (3u << 20));
    float*  part  = (float*)(ws + (3u << 20) + (32u << 10));
    __bf16* Wt    = (__bf16*)(ws + (3u << 20) + (544u << 10));

    k0_wt<<<96, 256, 0, stream>>>(Wq, Wk, Wv, Wt);
    k1_fused<<<512, 256, 0, stream>>>(x, Wt, bq, bk, bv, Qbf, Kbf, Vt);
    k2_cs<<<1024, 256, 0, stream>>>(Qbf, Kbf, part);
    k2b<<<32, 256, 0, stream>>>(part, rarr);
    kb_pv<<<512, 256, 0, stream>>>(Qbf, Kbf, Vt, rarr, out);
    ka_mv<<<512, 256, 0, stream>>>(Vt, mask, out);
}